// Round 9
// baseline (113.394 us; speedup 1.0000x reference)
//
#include <hip/hip_runtime.h>
#include <math.h>

// Problem constants
constexpr int L  = 4096;    // seq len
constexpr int D  = 1024;    // d_model
constexpr int N  = 16;      // hiddens per channel
constexpr int NC = 128;     // chunks
constexpr int T  = L / NC;  // 32 steps per chunk
constexpr int DG = 64;      // channels per block
constexpr int G  = D / DG;  // 16 d-groups

__device__ __forceinline__ float softplus_f(float v) {
    return fmaxf(v, 0.0f) + log1pf(expf(-fabsf(v)));
}

// Fast Lambda = exp(dt*(ar + i*ai)) via HW transcendentals.
__device__ __forceinline__ void lam_fast(float ar, float ai, float dt,
                                         float& lr, float& li) {
    float e = __expf(ar * dt);
    float s, c;
    __sincosf(ai * dt, &s, &c);
    lr = e * c;
    li = e * s;
}

// K1: thread = (c, d, q): 4 states (n = q*4+j). Local scan, zero init.
// x staged via LDS (8 KiB). 2048 blocks -> 8 blocks/CU, 8 waves/SIMD for
// latency hiding. End states -> s2[c][n][d] (coalesced for k_scan).
__global__ __launch_bounds__(256, 8) void k_local(
    const float* __restrict__ x,
    const float* __restrict__ Delta,
    const float* __restrict__ A_re, const float* __restrict__ A_im,
    float2* __restrict__ s2)
{
    __shared__ float xs[T * DG];          // 8 KiB
    const int c  = blockIdx.x >> 4;       // chunk
    const int dg = blockIdx.x & 15;       // d-group
    const int t  = threadIdx.x;

    const float* xg = x + (size_t)c * T * D + dg * DG;
    #pragma unroll
    for (int it = 0; it < 2; ++it) {      // 2048 floats, float4-coalesced
        int f = t * 4 + it * 1024;
        int row = f >> 6, col = f & 63;
        *(float4*)&xs[row * DG + col] =
            *(const float4*)(xg + (size_t)row * D + col);
    }

    const int q = t & 3, dl = t >> 2;
    const int d = dg * DG + dl;
    const float dt = softplus_f(Delta[d]);
    float Lr[4], Li[4];
    {
        float4 a0 = *(const float4*)(A_re + d * N + q * 4);
        float4 a1 = *(const float4*)(A_im + d * N + q * 4);
        const float ar[4] = {a0.x, a0.y, a0.z, a0.w};
        const float ai[4] = {a1.x, a1.y, a1.z, a1.w};
        #pragma unroll
        for (int j = 0; j < 4; ++j) lam_fast(ar[j], ai[j], dt, Lr[j], Li[j]);
    }
    __syncthreads();

    float gr[4] = {0, 0, 0, 0}, gi[4] = {0, 0, 0, 0};
    #pragma unroll
    for (int i = 0; i < T; ++i) {
        float xv = xs[i * DG + dl];
        #pragma unroll
        for (int j = 0; j < 4; ++j) {
            float t2 = fmaf(-Li[j], gi[j], xv);
            float nr = fmaf(Lr[j], gr[j], t2);
            gi[j] = fmaf(Lr[j], gi[j], Li[j] * gr[j]);
            gr[j] = nr;
        }
    }
    #pragma unroll
    for (int j = 0; j < 4; ++j)
        s2[((size_t)c * N + q * 4 + j) * D + d] = make_float2(gr[j], gi[j]);
}

// K2: thread = (n,d): serial scan over NC chunk states, in-place -> carry
// before each chunk. 256 blocks x 64 threads (1 wave/CU, all CUs' memory
// queues engaged). 32-deep batches: 4 serial latency episodes.
__global__ __launch_bounds__(64) void k_scan(
    const float* __restrict__ Delta,
    const float* __restrict__ A_re, const float* __restrict__ A_im,
    float2* __restrict__ s2)
{
    const int tid = blockIdx.x * 64 + threadIdx.x;   // n*D + d
    const int d = tid & (D - 1);
    const int n = tid >> 10;

    const float dt = softplus_f(Delta[d]);
    float Lr, Li;
    lam_fast(A_re[d * N + n], A_im[d * N + n], dt, Lr, Li);
    #pragma unroll
    for (int k = 0; k < 5; ++k) {         // Lam^32 (T = 32)
        float nr = Lr * Lr - Li * Li;
        Li = 2.0f * Lr * Li;
        Lr = nr;
    }

    float cr = 0.0f, ci = 0.0f;
    #pragma unroll
    for (int c0 = 0; c0 < NC; c0 += 32) {
        float2 sv[32];
        #pragma unroll
        for (int u = 0; u < 32; ++u)
            sv[u] = s2[(size_t)(c0 + u) * (N * D) + tid];
        #pragma unroll
        for (int u = 0; u < 32; ++u) {
            s2[(size_t)(c0 + u) * (N * D) + tid] = make_float2(cr, ci);
            float nr = fmaf(Lr, cr, fmaf(-Li, ci, sv[u].x));
            ci = fmaf(Lr, ci, fmaf(Li, cr, sv[u].y));
            cr = nr;
        }
    }
}

// K3: thread = (c, d, q): re-run scan from carry for 4 states, contract with
// C' = dt*C*B, butterfly-reduce over q, add D*x, full-lane rotated stores.
__global__ __launch_bounds__(256, 8) void k_out(
    const float* __restrict__ x,
    const float* __restrict__ Delta,
    const float* __restrict__ A_re, const float* __restrict__ A_im,
    const float* __restrict__ B_re, const float* __restrict__ B_im,
    const float* __restrict__ C_re, const float* __restrict__ C_im,
    const float* __restrict__ Dp,
    const float2* __restrict__ s2,
    float* __restrict__ out)
{
    __shared__ float xs[T * DG];          // 8 KiB
    const int c  = blockIdx.x >> 4;
    const int dg = blockIdx.x & 15;
    const int t  = threadIdx.x;

    const float* xg = x + (size_t)c * T * D + dg * DG;
    #pragma unroll
    for (int it = 0; it < 2; ++it) {
        int f = t * 4 + it * 1024;
        int row = f >> 6, col = f & 63;
        *(float4*)&xs[row * DG + col] =
            *(const float4*)(xg + (size_t)row * D + col);
    }

    const int q = t & 3, dl = t >> 2;
    const int d = dg * DG + dl;
    const float dt  = softplus_f(Delta[d]);
    const float dpv = Dp[d];

    float Lr[4], Li[4], Cr[4], Ci[4], gr[4], gi[4];
    {
        const int pidx = d * N + q * 4;
        float4 a0 = *(const float4*)(A_re + pidx);
        float4 a1 = *(const float4*)(A_im + pidx);
        float4 b0 = *(const float4*)(B_re + pidx);
        float4 b1 = *(const float4*)(B_im + pidx);
        float4 c0 = *(const float4*)(C_re + pidx);
        float4 c1 = *(const float4*)(C_im + pidx);
        const float ar[4] = {a0.x, a0.y, a0.z, a0.w};
        const float ai[4] = {a1.x, a1.y, a1.z, a1.w};
        const float br[4] = {b0.x, b0.y, b0.z, b0.w};
        const float bi[4] = {b1.x, b1.y, b1.z, b1.w};
        const float crr[4] = {c0.x, c0.y, c0.z, c0.w};
        const float cii[4] = {c1.x, c1.y, c1.z, c1.w};
        #pragma unroll
        for (int j = 0; j < 4; ++j) {
            lam_fast(ar[j], ai[j], dt, Lr[j], Li[j]);
            Cr[j] = dt * (crr[j] * br[j] - cii[j] * bi[j]);
            Ci[j] = dt * (crr[j] * bi[j] + cii[j] * br[j]);
        }
    }
    #pragma unroll
    for (int j = 0; j < 4; ++j) {
        float2 cv = s2[((size_t)c * N + q * 4 + j) * D + d];
        gr[j] = cv.x; gi[j] = cv.y;
    }
    float* og = out + (size_t)c * T * D + dg * DG;
    __syncthreads();

    #pragma unroll
    for (int ib = 0; ib < T / 4; ++ib) {
        float keep = 0.0f;
        #pragma unroll
        for (int u = 0; u < 4; ++u) {
            int i = ib * 4 + u;
            float xv = xs[i * DG + dl];
            float acc = 0.0f;
            #pragma unroll
            for (int j = 0; j < 4; ++j) {
                float t2 = fmaf(-Li[j], gi[j], xv);
                float nr = fmaf(Lr[j], gr[j], t2);
                gi[j] = fmaf(Lr[j], gi[j], Li[j] * gr[j]);
                gr[j] = nr;
                acc = fmaf(Cr[j], gr[j], acc);
                acc = fmaf(-Ci[j], gi[j], acc);
            }
            acc += __shfl_xor(acc, 1);    // reduce over q-pairs
            acc += __shfl_xor(acc, 2);
            acc = fmaf(dpv, xv, acc);     // every lane has the full sum
            keep = (q == u) ? acc : keep; // lane q keeps iteration u==q
        }
        og[(size_t)(ib * 4 + q) * D + dl] = keep;  // all 64 lanes store
    }
}

extern "C" void kernel_launch(void* const* d_in, const int* in_sizes, int n_in,
                              void* d_out, int out_size, void* d_ws, size_t ws_size,
                              hipStream_t stream) {
    const float* x     = (const float*)d_in[0];
    const float* Delta = (const float*)d_in[1];
    const float* A_re  = (const float*)d_in[2];
    const float* A_im  = (const float*)d_in[3];
    const float* B_re  = (const float*)d_in[4];
    const float* B_im  = (const float*)d_in[5];
    const float* C_re  = (const float*)d_in[6];
    const float* C_im  = (const float*)d_in[7];
    const float* Dp    = (const float*)d_in[8];
    float* out = (float*)d_out;
    float2* s2 = (float2*)d_ws;   // NC * N * D float2 = 16 MiB

    k_local<<<NC * G, 256, 0, stream>>>(x, Delta, A_re, A_im, s2);
    k_scan<<<(N * D) / 64, 64, 0, stream>>>(Delta, A_re, A_im, s2);
    k_out<<<NC * G, 256, 0, stream>>>(x, Delta, A_re, A_im, B_re, B_im,
                                      C_re, C_im, Dp, s2, out);
}